// Round 19
// baseline (172.058 us; speedup 1.0000x reference)
//
#include <hip/hip_runtime.h>

// VQ-VAE quantization, round 19: fit under the 64-VGPR cliff for 8 waves/SIMD.
// r18 structure (129us) with per-wave state halved: PPB=32 (rt=2 -> afr 16,
// acc 8, mthr 8 regs), depth-2 prefetch (2 slots), h in LDS (BT float-free).
// __launch_bounds__(256,8) pins VGPR<=64 (estimated need ~55-60; r8's mistake
// was forcing 64 while needing ~100). Grid 2048; LDS ~25.6KB -> 6 blocks/CU
// -> 24 waves/CU resident (1.5x all prior rounds).
// Carried: persistent mthr MFMA C-in, affine pad-backed prefetch, sign-mask +
// ctz push, sampled threshold (8 of 64 tiles/wave, cross-wave max) - DELTA,
// exact fp32 rescore + LDS atomicMin((ordbits(dist)<<32)|code) -> exact
// argmin, first-index ties (jnp.argmin semantics). DELTA=0.25 >= 2x worst
// bf16 dot error -> true winner always pushed.

#define NPTS    65536
#define CDIM    64
#define KCODES  4096
#define WAVES   4
#define PPB     32                 // points per block
#define KPW     (KCODES / WAVES)   // 1024 codes per wave
#define TILES   (KPW / 16)         // 64 tiles of 16 codes
#define PADC    64                 // pad codes (prefetch overrun target)
#define LISTCAP 1536
#define DELTA   0.25f

typedef __attribute__((ext_vector_type(8))) short short8;
typedef __attribute__((ext_vector_type(4))) float f32x4;

__device__ __forceinline__ unsigned short f2bf(float x) {
    unsigned u = __float_as_uint(x);
    return (unsigned short)((u + 0x7FFFu + ((u >> 16) & 1u)) >> 16);  // RNE
}

struct BT { short8 b0, b1; };

// cb fp32 -> bf16 copy + h[k] = 0.5*||e_k||^2
__global__ __launch_bounds__(256) void vq_prep(const float* __restrict__ cb,
                                               short* __restrict__ cbb,
                                               float* __restrict__ h) {
    int k = blockIdx.x * 256 + threadIdx.x;
    const float4* p = reinterpret_cast<const float4*>(cb + (size_t)k * CDIM);
    float s0 = 0.f, s1 = 0.f, s2 = 0.f, s3 = 0.f;
#pragma unroll
    for (int i = 0; i < 16; i += 2) {
        float4 va = p[i], vb = p[i + 1];
        s0 = fmaf(va.x, va.x, s0); s1 = fmaf(va.y, va.y, s1);
        s2 = fmaf(va.z, va.z, s2); s3 = fmaf(va.w, va.w, s3);
        s0 = fmaf(vb.x, vb.x, s0); s1 = fmaf(vb.y, vb.y, s1);
        s2 = fmaf(vb.z, vb.z, s2); s3 = fmaf(vb.w, vb.w, s3);
        short8 o;
        o[0] = (short)f2bf(va.x); o[1] = (short)f2bf(va.y);
        o[2] = (short)f2bf(va.z); o[3] = (short)f2bf(va.w);
        o[4] = (short)f2bf(vb.x); o[5] = (short)f2bf(vb.y);
        o[6] = (short)f2bf(vb.z); o[7] = (short)f2bf(vb.w);
        *reinterpret_cast<short8*>(cbb + (size_t)k * CDIM + i * 4) = o;
    }
    h[k] = 0.5f * ((s0 + s1) + (s2 + s3));
}

__global__ __launch_bounds__(256, 8) void vq_main(const float* __restrict__ enc,
                                                  const float* __restrict__ cbf,
                                                  const short* __restrict__ cbb,
                                                  const float* __restrict__ h,
                                                  float* __restrict__ out) {
    __shared__ unsigned list[LISTCAP];
    __shared__ float hlds[KCODES + PADC];
    __shared__ float rowmax[WAVES][PPB];
    __shared__ float thrL[PPB];
    __shared__ unsigned long long mkey[PPB];
    __shared__ unsigned lcnt;

    const int tid  = threadIdx.x;
    const int wid  = tid >> 6, lane = tid & 63;
    const int lrow = lane & 15, lseg = lane >> 4;
    const int pbase = blockIdx.x * PPB;    // 32 points per block
    const int k0 = wid * KPW;              // this wave's 1024-code slice

    if (tid == 0) lcnt = 0;
    if (tid < PPB) mkey[tid] = ~0ull;
    for (int i = tid; i < KCODES + PADC; i += 256) hlds[i] = h[i];

    // ---- A fragments: the block's 32 points as bf16 (rt = 2 row-tiles) ----
    // 16x16x32 A layout: row = lane&15, k = (lane>>4)*8 + e (+32 per kk)
    short8 afr[2][2];
#pragma unroll
    for (int rt = 0; rt < 2; ++rt)
#pragma unroll
        for (int kk = 0; kk < 2; ++kk) {
            const float4* xp = reinterpret_cast<const float4*>(
                enc + (size_t)(pbase + rt * 16 + lrow) * CDIM + kk * 32 + lseg * 8);
            float4 v0 = xp[0], v1 = xp[1];
            short8 a;
            a[0] = (short)f2bf(v0.x); a[1] = (short)f2bf(v0.y);
            a[2] = (short)f2bf(v0.z); a[3] = (short)f2bf(v0.w);
            a[4] = (short)f2bf(v1.x); a[5] = (short)f2bf(v1.y);
            a[6] = (short)f2bf(v1.z); a[7] = (short)f2bf(v1.w);
            afr[rt][kk] = a;
        }
    __syncthreads();   // hlds + lcnt/mkey visible

    auto loadB = [&](int ct, BT& s) {
        int code = k0 + ct * 16 + lrow;    // may run PADC past KCODES (pad-backed)
        const short* base = cbb + (size_t)code * CDIM + lseg * 8;
        s.b0 = *reinterpret_cast<const short8*>(base);
        s.b1 = *reinterpret_cast<const short8*>(base + 32);
    };

    // ---- sample sweep: tiles {0,8,...,56}, row max only, depth-2 ----
    f32x4 best[2];
#pragma unroll
    for (int rt = 0; rt < 2; ++rt)
#pragma unroll
        for (int i = 0; i < 4; ++i) best[rt][i] = -__builtin_inff();

    {
        BT s0, s1;
        loadB(0, s0); loadB(8, s1);
#define SSBODY(SLOT, J)                                                        \
        {                                                                      \
            float nh = -hlds[k0 + (J) * 128 + lrow];                           \
            f32x4 acc[2];                                                      \
            _Pragma("unroll")                                                  \
            for (int rt = 0; rt < 2; ++rt) {                                   \
                acc[rt][0] = nh; acc[rt][1] = nh;                              \
                acc[rt][2] = nh; acc[rt][3] = nh;                              \
            }                                                                  \
            _Pragma("unroll")                                                  \
            for (int rt = 0; rt < 2; ++rt)                                     \
                acc[rt] = __builtin_amdgcn_mfma_f32_16x16x32_bf16(afr[rt][0], SLOT.b0, acc[rt], 0, 0, 0); \
            _Pragma("unroll")                                                  \
            for (int rt = 0; rt < 2; ++rt)                                     \
                acc[rt] = __builtin_amdgcn_mfma_f32_16x16x32_bf16(afr[rt][1], SLOT.b1, acc[rt], 0, 0, 0); \
            _Pragma("unroll")                                                  \
            for (int rt = 0; rt < 2; ++rt)                                     \
                _Pragma("unroll")                                              \
                for (int i = 0; i < 4; ++i)                                    \
                    best[rt][i] = fmaxf(best[rt][i], acc[rt][i]);              \
            loadB((((J) + 2) & 7) * 8, SLOT);                                  \
        }
        SSBODY(s0, 0) SSBODY(s1, 1)
        SSBODY(s0, 2) SSBODY(s1, 3)
        SSBODY(s0, 4) SSBODY(s1, 5)
        SSBODY(s0, 6) SSBODY(s1, 7)
#undef SSBODY
    }

    // intra-wave max over the 16 col-lanes
#pragma unroll
    for (int m = 1; m <= 8; m <<= 1)
#pragma unroll
        for (int rt = 0; rt < 2; ++rt)
#pragma unroll
            for (int i = 0; i < 4; ++i)
                best[rt][i] = fmaxf(best[rt][i], __shfl_xor(best[rt][i], m, 64));
    if (lrow == 0) {   // lanes 0,16,32,48 cover all 32 rows
#pragma unroll
        for (int rt = 0; rt < 2; ++rt)
#pragma unroll
            for (int i = 0; i < 4; ++i)
                rowmax[wid][rt * 16 + lseg * 4 + i] = best[rt][i];
    }
    __syncthreads();
    if (tid < PPB) {   // cross-wave max of sampled maxes -> threshold
        float m0 = fmaxf(rowmax[0][tid], rowmax[1][tid]);
        float m1 = fmaxf(rowmax[2][tid], rowmax[3][tid]);
        thrL[tid] = fmaxf(m0, m1) - DELTA;
    }
    __syncthreads();

    // mthr = -thr, persistent MFMA C-in for the whole sweep
    f32x4 mthr[2];
#pragma unroll
    for (int rt = 0; rt < 2; ++rt)
#pragma unroll
        for (int i = 0; i < 4; ++i) mthr[rt][i] = -thrL[rt * 16 + lseg * 4 + i];

    // ---- sweep 2: C-in = mthr; hh from LDS; test acc >= hh; ctz push ----
    {
        BT s0, s1;
        loadB(0, s0); loadB(1, s1);
#define S2BODY(SLOT, T)                                                        \
        {                                                                      \
            float hh = hlds[k0 + (T) * 16 + lrow];                             \
            f32x4 acc[2];                                                      \
            _Pragma("unroll")                                                  \
            for (int rt = 0; rt < 2; ++rt)                                     \
                acc[rt] = __builtin_amdgcn_mfma_f32_16x16x32_bf16(afr[rt][0], SLOT.b0, mthr[rt], 0, 0, 0); \
            _Pragma("unroll")                                                  \
            for (int rt = 0; rt < 2; ++rt)                                     \
                acc[rt] = __builtin_amdgcn_mfma_f32_16x16x32_bf16(afr[rt][1], SLOT.b1, acc[rt], 0, 0, 0); \
            unsigned mask = 0u;                                                \
            _Pragma("unroll")                                                  \
            for (int rt = 0; rt < 2; ++rt)                                     \
                _Pragma("unroll")                                              \
                for (int i = 0; i < 4; ++i)                                    \
                    mask |= (acc[rt][i] >= hh) ? (1u << (rt * 4 + i)) : 0u;    \
            if (mask) {                                                        \
                unsigned code = (unsigned)(k0 + (T) * 16 + lrow);              \
                do {                                                           \
                    int kz = __builtin_ctz(mask);                              \
                    mask &= mask - 1u;                                         \
                    unsigned row = ((unsigned)(kz >> 2) << 4)                  \
                                 + (unsigned)(lseg * 4) + (unsigned)(kz & 3);  /* C/D map (m89) */ \
                    unsigned pos = atomicAdd(&lcnt, 1u);                       \
                    if (pos < LISTCAP) list[pos] = (row << 12) | code;         \
                } while (mask);                                                \
            }                                                                  \
            loadB((T) + 2, SLOT);   /* affine; pad-backed past TILES */        \
        }
        for (int t = 0; t < TILES; t += 2) {
            S2BODY(s0, t + 0)
            S2BODY(s1, t + 1)
        }
#undef S2BODY
    }
    __syncthreads();

    // ---- exact fp32 rescore: 4 lanes per candidate (coalesced 256B) ----
    unsigned cnt = lcnt; if (cnt > LISTCAP) cnt = LISTCAP;
    for (unsigned t4 = tid; t4 < cnt * 4; t4 += 256) {
        unsigned t = t4 >> 2; int q = t4 & 3;
        unsigned e = list[t];
        int row = (int)(e >> 12), c = (int)(e & 4095u);
        const float4* xp = reinterpret_cast<const float4*>(enc + (size_t)(pbase + row) * CDIM) + q * 4;
        const float4* ep = reinterpret_cast<const float4*>(cbf + (size_t)c * CDIM) + q * 4;
        float a0 = 0.f, a1 = 0.f, a2 = 0.f, a3 = 0.f;
#pragma unroll
        for (int i = 0; i < 4; ++i) {
            float4 xv = xp[i], ev = ep[i];
            a0 = fmaf(xv.x, ev.x, a0); a1 = fmaf(xv.y, ev.y, a1);
            a2 = fmaf(xv.z, ev.z, a2); a3 = fmaf(xv.w, ev.w, a3);
        }
        float p = (a0 + a1) + (a2 + a3);
        p += __shfl_xor(p, 1, 64);
        p += __shfl_xor(p, 2, 64);               // full dot in all 4 lanes
        if (q == 0) {
            float d2 = fmaf(-2.f, p, 2.f * hlds[c]);  // esq - 2*dot (bit-identical everywhere)
            unsigned bb = __float_as_uint(d2);
            unsigned ord = bb ^ (unsigned)(((int)bb >> 31) | 0x80000000);  // monotonic
            atomicMin(&mkey[row], ((unsigned long long)ord << 32) | (unsigned)c);
        }
    }
    __syncthreads();

    // ---- finalize: gather winner rows (8 threads per point) + idx ----
    {
        int p = tid >> 3, q = tid & 7;
        int c = (int)(mkey[p] & 4095u);
        const float4* ep = reinterpret_cast<const float4*>(cbf + (size_t)c * CDIM);
        float4* op = reinterpret_cast<float4*>(out + (size_t)(pbase + p) * CDIM);
        op[q] = ep[q];
        op[q + 8] = ep[q + 8];
        if (tid < PPB)
            out[(size_t)NPTS * CDIM + pbase + tid] = (float)(mkey[tid] & 4095u);
    }
}

extern "C" void kernel_launch(void* const* d_in, const int* in_sizes, int n_in,
                              void* d_out, int out_size, void* d_ws, size_t ws_size,
                              hipStream_t stream) {
    const float* enc = (const float*)d_in[0];
    const float* cb  = (const float*)d_in[1];
    float* out = (float*)d_out;

    // ws: cbb bf16[(4096+64)*64] (520KB) | h fp32[4096+64]
    short* cbb = (short*)d_ws;
    float* hws = (float*)(cbb + (size_t)(KCODES + PADC) * CDIM);

    vq_prep<<<KCODES / 256, 256, 0, stream>>>(cb, cbb, hws);
    vq_main<<<NPTS / PPB, 256, 0, stream>>>(enc, cb, cbb, hws, out);
}

// Round 20
// 113.176 us; speedup vs baseline: 1.5203x; 1.5203x over previous
//
#include <hip/hip_runtime.h>

// VQ-VAE quantization, round 20: r18 (129us) + basic-block consolidation.
// The per-tile `if(mask) push` put every 8-MFMA body in its own basic block,
// serializing {MFMA latency -> cmp -> branch -> join} per tile inside each
// wave. Fix: branchless 16-bit mask per tile, OR'd into a 64-bit group mask
// over 4 tiles; ONE `if(gm){ctzll decode+push}` per group. 32 MFMAs + 4
// hh-reads + 4 prefetches now share a basic block -> cross-tile overlap.
// Push set is bit-identical to r18 (tile recovered from bit/16).
// Carried: h in LDS, persistent mthr C-in, affine pad-backed depth-4
// prefetch, sampled threshold (8/64 tiles/wave + cross-wave max) - DELTA,
// exact fp32 rescore + LDS atomicMin((ordbits(dist)<<32)|code) -> exact
// argmin, first-index ties. DELTA=0.25 >= 2x worst bf16 dot error.

#define NPTS    65536
#define CDIM    64
#define KCODES  4096
#define WAVES   4
#define KPW     (KCODES / WAVES)   // 1024 codes per wave
#define TILES   (KPW / 16)         // 64 tiles of 16 codes
#define PADC    64                 // pad codes (prefetch overrun target)
#define LISTCAP 4096
#define DELTA   0.25f

typedef __attribute__((ext_vector_type(8))) short short8;
typedef __attribute__((ext_vector_type(4))) float f32x4;

__device__ __forceinline__ unsigned short f2bf(float x) {
    unsigned u = __float_as_uint(x);
    return (unsigned short)((u + 0x7FFFu + ((u >> 16) & 1u)) >> 16);  // RNE
}

struct BT { short8 b0, b1; };

// cb fp32 -> bf16 copy + h[k] = 0.5*||e_k||^2
__global__ __launch_bounds__(256) void vq_prep(const float* __restrict__ cb,
                                               short* __restrict__ cbb,
                                               float* __restrict__ h) {
    int k = blockIdx.x * 256 + threadIdx.x;
    const float4* p = reinterpret_cast<const float4*>(cb + (size_t)k * CDIM);
    float s0 = 0.f, s1 = 0.f, s2 = 0.f, s3 = 0.f;
#pragma unroll
    for (int i = 0; i < 16; i += 2) {
        float4 va = p[i], vb = p[i + 1];
        s0 = fmaf(va.x, va.x, s0); s1 = fmaf(va.y, va.y, s1);
        s2 = fmaf(va.z, va.z, s2); s3 = fmaf(va.w, va.w, s3);
        s0 = fmaf(vb.x, vb.x, s0); s1 = fmaf(vb.y, vb.y, s1);
        s2 = fmaf(vb.z, vb.z, s2); s3 = fmaf(vb.w, vb.w, s3);
        short8 o;
        o[0] = (short)f2bf(va.x); o[1] = (short)f2bf(va.y);
        o[2] = (short)f2bf(va.z); o[3] = (short)f2bf(va.w);
        o[4] = (short)f2bf(vb.x); o[5] = (short)f2bf(vb.y);
        o[6] = (short)f2bf(vb.z); o[7] = (short)f2bf(vb.w);
        *reinterpret_cast<short8*>(cbb + (size_t)k * CDIM + i * 4) = o;
    }
    h[k] = 0.5f * ((s0 + s1) + (s2 + s3));
}

__global__ __launch_bounds__(256) void vq_main(const float* __restrict__ enc,
                                               const float* __restrict__ cbf,
                                               const short* __restrict__ cbb,
                                               const float* __restrict__ h,
                                               float* __restrict__ out) {
    __shared__ unsigned list[LISTCAP];
    __shared__ float hlds[KCODES + PADC];
    __shared__ float rowmax[WAVES][64];
    __shared__ float thrL[64];
    __shared__ unsigned long long mkey[64];
    __shared__ unsigned lcnt;

    const int tid  = threadIdx.x;
    const int wid  = tid >> 6, lane = tid & 63;
    const int lrow = lane & 15, lseg = lane >> 4;
    const int pbase = blockIdx.x * 64;     // 64 points per block
    const int k0 = wid * KPW;              // this wave's 1024-code slice

    if (tid == 0) lcnt = 0;
    if (tid < 64) mkey[tid] = ~0ull;
    for (int i = tid; i < KCODES + PADC; i += 256) hlds[i] = h[i];

    // ---- A fragments: the block's 64 points as bf16 ----
    // 16x16x32 A layout: row = lane&15, k = (lane>>4)*8 + e (+32 per kk)
    short8 afr[4][2];
#pragma unroll
    for (int rt = 0; rt < 4; ++rt)
#pragma unroll
        for (int kk = 0; kk < 2; ++kk) {
            const float4* xp = reinterpret_cast<const float4*>(
                enc + (size_t)(pbase + rt * 16 + lrow) * CDIM + kk * 32 + lseg * 8);
            float4 v0 = xp[0], v1 = xp[1];
            short8 a;
            a[0] = (short)f2bf(v0.x); a[1] = (short)f2bf(v0.y);
            a[2] = (short)f2bf(v0.z); a[3] = (short)f2bf(v0.w);
            a[4] = (short)f2bf(v1.x); a[5] = (short)f2bf(v1.y);
            a[6] = (short)f2bf(v1.z); a[7] = (short)f2bf(v1.w);
            afr[rt][kk] = a;
        }
    __syncthreads();   // hlds + lcnt/mkey visible

    auto loadB = [&](int ct, BT& s) {
        int code = k0 + ct * 16 + lrow;    // may run PADC past KCODES (pad-backed)
        const short* base = cbb + (size_t)code * CDIM + lseg * 8;
        s.b0 = *reinterpret_cast<const short8*>(base);
        s.b1 = *reinterpret_cast<const short8*>(base + 32);
    };

    // ---- sample sweep: tiles {0,8,...,56}, row max only ----
    f32x4 best[4];
#pragma unroll
    for (int rt = 0; rt < 4; ++rt)
#pragma unroll
        for (int i = 0; i < 4; ++i) best[rt][i] = -__builtin_inff();

    {
        BT s0, s1, s2, s3;
        loadB(0, s0); loadB(8, s1); loadB(16, s2); loadB(24, s3);
#define SSBODY(SLOT, J)                                                        \
        {                                                                      \
            float nh = -hlds[k0 + (J) * 128 + lrow];                           \
            f32x4 acc[4];                                                      \
            _Pragma("unroll")                                                  \
            for (int rt = 0; rt < 4; ++rt) {                                   \
                acc[rt][0] = nh; acc[rt][1] = nh;                              \
                acc[rt][2] = nh; acc[rt][3] = nh;                              \
            }                                                                  \
            _Pragma("unroll")                                                  \
            for (int rt = 0; rt < 4; ++rt)                                     \
                acc[rt] = __builtin_amdgcn_mfma_f32_16x16x32_bf16(afr[rt][0], SLOT.b0, acc[rt], 0, 0, 0); \
            _Pragma("unroll")                                                  \
            for (int rt = 0; rt < 4; ++rt)                                     \
                acc[rt] = __builtin_amdgcn_mfma_f32_16x16x32_bf16(afr[rt][1], SLOT.b1, acc[rt], 0, 0, 0); \
            _Pragma("unroll")                                                  \
            for (int rt = 0; rt < 4; ++rt)                                     \
                _Pragma("unroll")                                              \
                for (int i = 0; i < 4; ++i)                                    \
                    best[rt][i] = fmaxf(best[rt][i], acc[rt][i]);              \
            loadB((((J) + 4) & 7) * 8, SLOT);                                  \
        }
        SSBODY(s0, 0) SSBODY(s1, 1) SSBODY(s2, 2) SSBODY(s3, 3)
        SSBODY(s0, 4) SSBODY(s1, 5) SSBODY(s2, 6) SSBODY(s3, 7)
#undef SSBODY
    }

    // intra-wave max over the 16 col-lanes
#pragma unroll
    for (int m = 1; m <= 8; m <<= 1)
#pragma unroll
        for (int rt = 0; rt < 4; ++rt)
#pragma unroll
            for (int i = 0; i < 4; ++i)
                best[rt][i] = fmaxf(best[rt][i], __shfl_xor(best[rt][i], m, 64));
    if (lrow == 0) {   // lanes 0,16,32,48 cover all 64 rows
#pragma unroll
        for (int rt = 0; rt < 4; ++rt)
#pragma unroll
            for (int i = 0; i < 4; ++i)
                rowmax[wid][rt * 16 + lseg * 4 + i] = best[rt][i];
    }
    __syncthreads();
    if (tid < 64) {    // cross-wave max of sampled maxes -> threshold
        float m0 = fmaxf(rowmax[0][tid], rowmax[1][tid]);
        float m1 = fmaxf(rowmax[2][tid], rowmax[3][tid]);
        thrL[tid] = fmaxf(m0, m1) - DELTA;
    }
    __syncthreads();

    // mthr = -thr, persistent MFMA C-in for the whole sweep
    f32x4 mthr[4];
#pragma unroll
    for (int rt = 0; rt < 4; ++rt)
#pragma unroll
        for (int i = 0; i < 4; ++i) mthr[rt][i] = -thrL[rt * 16 + lseg * 4 + i];

    // ---- sweep 2: 4-tile groups, branchless masks, ONE push per group ----
    {
        BT s0, s1, s2, s3;
        loadB(0, s0); loadB(1, s1); loadB(2, s2); loadB(3, s3);
#define GBODY(SLOT, G)                                                         \
        {                                                                      \
            float hh = hlds[k0 + (t + (G)) * 16 + lrow];                       \
            f32x4 acc[4];                                                      \
            _Pragma("unroll")                                                  \
            for (int rt = 0; rt < 4; ++rt)                                     \
                acc[rt] = __builtin_amdgcn_mfma_f32_16x16x32_bf16(afr[rt][0], SLOT.b0, mthr[rt], 0, 0, 0); \
            _Pragma("unroll")                                                  \
            for (int rt = 0; rt < 4; ++rt)                                     \
                acc[rt] = __builtin_amdgcn_mfma_f32_16x16x32_bf16(afr[rt][1], SLOT.b1, acc[rt], 0, 0, 0); \
            unsigned m = 0u;                                                   \
            _Pragma("unroll")                                                  \
            for (int rt = 0; rt < 4; ++rt)                                     \
                _Pragma("unroll")                                              \
                for (int i = 0; i < 4; ++i)                                    \
                    m |= (acc[rt][i] >= hh) ? (1u << (rt * 4 + i)) : 0u;       \
            gm |= (unsigned long long)m << ((G) * 16);                         \
            loadB(t + (G) + 4, SLOT);   /* affine; pad-backed past TILES */    \
        }
        for (int t = 0; t < TILES; t += 4) {
            unsigned long long gm = 0ull;
            GBODY(s0, 0)
            GBODY(s1, 1)
            GBODY(s2, 2)
            GBODY(s3, 3)
            if (gm) {
                do {
                    int kz = __builtin_ctzll(gm);
                    gm &= gm - 1ull;
                    int g = kz >> 4, e = kz & 15;
                    unsigned row = ((unsigned)(e >> 2) << 4)
                                 + (unsigned)(lseg * 4) + (unsigned)(e & 3);   // C/D map (m89)
                    unsigned code = (unsigned)(k0 + (t + g) * 16 + lrow);
                    unsigned pos = atomicAdd(&lcnt, 1u);
                    if (pos < LISTCAP) list[pos] = (row << 12) | code;
                } while (gm);
            }
        }
#undef GBODY
    }
    __syncthreads();

    // ---- exact fp32 rescore: 4 lanes per candidate (coalesced 256B) ----
    unsigned cnt = lcnt; if (cnt > LISTCAP) cnt = LISTCAP;
    for (unsigned t4 = tid; t4 < cnt * 4; t4 += 256) {
        unsigned t = t4 >> 2; int q = t4 & 3;
        unsigned e = list[t];
        int row = (int)(e >> 12), c = (int)(e & 4095u);
        const float4* xp = reinterpret_cast<const float4*>(enc + (size_t)(pbase + row) * CDIM) + q * 4;
        const float4* ep = reinterpret_cast<const float4*>(cbf + (size_t)c * CDIM) + q * 4;
        float a0 = 0.f, a1 = 0.f, a2 = 0.f, a3 = 0.f;
#pragma unroll
        for (int i = 0; i < 4; ++i) {
            float4 xv = xp[i], ev = ep[i];
            a0 = fmaf(xv.x, ev.x, a0); a1 = fmaf(xv.y, ev.y, a1);
            a2 = fmaf(xv.z, ev.z, a2); a3 = fmaf(xv.w, ev.w, a3);
        }
        float p = (a0 + a1) + (a2 + a3);
        p += __shfl_xor(p, 1, 64);
        p += __shfl_xor(p, 2, 64);               // full dot in all 4 lanes
        if (q == 0) {
            float d2 = fmaf(-2.f, p, 2.f * hlds[c]);  // esq - 2*dot (bit-identical everywhere)
            unsigned bb = __float_as_uint(d2);
            unsigned ord = bb ^ (unsigned)(((int)bb >> 31) | 0x80000000);  // monotonic
            atomicMin(&mkey[row], ((unsigned long long)ord << 32) | (unsigned)c);
        }
    }
    __syncthreads();

    // ---- finalize: gather winner rows (4 threads per point) + idx ----
    {
        int p = tid >> 2, q = tid & 3;
        int c = (int)(mkey[p] & 4095u);
        const float4* ep = reinterpret_cast<const float4*>(cbf + (size_t)c * CDIM) + q * 4;
        float4* op = reinterpret_cast<float4*>(out + (size_t)(pbase + p) * CDIM) + q * 4;
#pragma unroll
        for (int i = 0; i < 4; ++i) op[i] = ep[i];
        if (tid < 64)
            out[(size_t)NPTS * CDIM + pbase + tid] = (float)(mkey[tid] & 4095u);
    }
}

extern "C" void kernel_launch(void* const* d_in, const int* in_sizes, int n_in,
                              void* d_out, int out_size, void* d_ws, size_t ws_size,
                              hipStream_t stream) {
    const float* enc = (const float*)d_in[0];
    const float* cb  = (const float*)d_in[1];
    float* out = (float*)d_out;

    // ws: cbb bf16[(4096+64)*64] (520KB) | h fp32[4096+64]
    short* cbb = (short*)d_ws;
    float* hws = (float*)(cbb + (size_t)(KCODES + PADC) * CDIM);

    vq_prep<<<KCODES / 256, 256, 0, stream>>>(cb, cbb, hws);
    vq_main<<<NPTS / 64, 256, 0, stream>>>(enc, cb, cbb, hws, out);
}